// Round 10
// baseline (1330.290 us; speedup 1.0000x reference)
//
#include <hip/hip_runtime.h>
#include <math.h>

#define BDIM 8
#define CDIM 64
#define HDIM 256
#define WDIM 256
#define HW  (HDIM*WDIM)   // 65536
#define HW2 (128*128)     // 16384
#define C4  256
#define C6  384

typedef __attribute__((ext_vector_type(8))) short short8;
typedef __attribute__((ext_vector_type(4))) float f32x4;

__device__ __forceinline__ ushort f2bf(float x) {
    unsigned u = __float_as_uint(x);
    unsigned r = (u + 0x7fffu + ((u >> 16) & 1u)) >> 16;
    return (ushort)r;
}
__device__ __forceinline__ float bf2f(ushort v) {
    return __uint_as_float(((unsigned)v) << 16);
}
__device__ __forceinline__ float gelu(float x) {
    return 0.5f * x * (1.0f + erff(x * 0.70710678118654752f));
}

// ---------------- weights f32 -> bf16 ----------------
__global__ void k_cvt_bf16(const float* __restrict__ src, ushort* __restrict__ dst, int n) {
    int i = blockIdx.x * 256 + threadIdx.x;
    if (i < n) dst[i] = f2bf(src[i]);
}

// ---------------- tail weight prep: W4L=W4*lw, Ka=b4+W4·lb, Ma=W4·lw, W5T ----------------
__global__ void k_prep(const float* __restrict__ W4, const float* __restrict__ b4,
                       const float* __restrict__ lw, const float* __restrict__ lb,
                       const float* __restrict__ W5,
                       float* __restrict__ W4L, float* __restrict__ KaMa,
                       float* __restrict__ W5T)
{
    int t = threadIdx.x; // 256
    if (t < 128) {
        float ka = b4[t], ma = 0.f;
        for (int c = 0; c < 64; ++c) {
            float w = W4[t * 64 + c];
            W4L[t * 64 + c] = w * lw[c];
            ka += w * lb[c];
            ma += w * lw[c];
        }
        KaMa[t] = ka;          // Ka for rows 0..127
        KaMa[128 + t] = ma;    // Ma for rows 0..127
    } else if (t < 192) {
        int o = t - 128;
        for (int j = 0; j < 64; ++j)
            W5T[j * 64 + o] = W5[o * 64 + j];
    }
}

// ---------------- LN1 + DWT fused (shuffle-split channel loop) ----------------
__global__ __launch_bounds__(256) void k_ln_dwt(
    const float* __restrict__ X, const float* __restrict__ filt,
    const float* __restrict__ lw, const float* __restrict__ lb,
    ushort* __restrict__ S)
{
    const int b   = blockIdx.z;
    const int tid = threadIdx.x;
    const int pb  = tid >> 2;
    const int cg  = tid & 3;
    const int p   = blockIdx.x * 64 + pb;
    const int h2  = p >> 6;
    const int wp  = p & 63;
    float f[16];
#pragma unroll
    for (int i = 0; i < 16; ++i) f[i] = filt[i];

    const float* xb = X + (size_t)b * CDIM * HW + (size_t)(2 * h2) * WDIM + 4 * wp;
    const int c0 = cg * 16;

    float s0 = 0.f, q0 = 0.f, s1 = 0.f, q1 = 0.f;
    for (int c = c0; c < c0 + 16; ++c) {
        const float* pr = xb + (size_t)c * HW;
        float4 r0 = *(const float4*)pr;
        float4 r1 = *(const float4*)(pr + WDIM);
        s0 += r0.x + r0.y + r1.x + r1.y;
        q0 += r0.x*r0.x + r0.y*r0.y + r1.x*r1.x + r1.y*r1.y;
        s1 += r0.z + r0.w + r1.z + r1.w;
        q1 += r0.z*r0.z + r0.w*r0.w + r1.z*r1.z + r1.w*r1.w;
    }
    s0 += __shfl_xor(s0, 1); q0 += __shfl_xor(q0, 1);
    s1 += __shfl_xor(s1, 1); q1 += __shfl_xor(q1, 1);
    s0 += __shfl_xor(s0, 2); q0 += __shfl_xor(q0, 2);
    s1 += __shfl_xor(s1, 2); q1 += __shfl_xor(q1, 2);
    const float inv = 1.0f / 64.0f;
    float m0 = s0 * inv, m1 = s1 * inv;
    float rs0 = rsqrtf(fmaxf(q0 * inv - m0 * m0, 0.f) + 1e-6f);
    float rs1 = rsqrtf(fmaxf(q1 * inv - m1 * m1, 0.f) + 1e-6f);

    const int n = h2 * 128 + 2 * wp;
    ushort* Sp = S + (size_t)b * C4 * HW2;
    for (int c = c0; c < c0 + 16; ++c) {
        const float* pr = xb + (size_t)c * HW;
        float4 r0 = *(const float4*)pr;
        float4 r1 = *(const float4*)(pr + WDIM);
        float wv = lw[c], bv = lb[c];
        float a00 = (r0.x - m0) * rs0 * wv + bv;
        float a01 = (r0.y - m0) * rs0 * wv + bv;
        float a10 = (r1.x - m0) * rs0 * wv + bv;
        float a11 = (r1.y - m0) * rs0 * wv + bv;
        float b00 = (r0.z - m1) * rs1 * wv + bv;
        float b01 = (r0.w - m1) * rs1 * wv + bv;
        float b10 = (r1.z - m1) * rs1 * wv + bv;
        float b11 = (r1.w - m1) * rs1 * wv + bv;
#pragma unroll
        for (int k = 0; k < 4; ++k) {
            float va = f[k*4+0]*a00 + f[k*4+1]*a01 + f[k*4+2]*a10 + f[k*4+3]*a11;
            float vb = f[k*4+0]*b00 + f[k*4+1]*b01 + f[k*4+2]*b10 + f[k*4+3]*b11;
            unsigned pk = (unsigned)f2bf(va) | ((unsigned)f2bf(vb) << 16);
            *(unsigned*)&Sp[(size_t)(k * CDIM + c) * HW2 + n] = pk;
        }
    }
}

// ---------------- pointwise conv: bf16 MFMA GEMM ----------------
template<bool BF16OUT>
__global__ __launch_bounds__(256) void k_pw_mfma(
    const ushort* __restrict__ A, const float* __restrict__ bias,
    const ushort* __restrict__ Xg, void* __restrict__ Yg,
    int M, int K, int N)
{
    const int b  = blockIdx.z;
    const int m0 = blockIdx.y * 128;
    const int n0 = blockIdx.x * 128;
    const ushort* X = Xg + (size_t)b * K * N;

    __shared__ ushort As[128][72];
    __shared__ ushort Bs[128][72];

    const int tid = threadIdx.x;
    const int l   = tid & 63, w = tid >> 6;
    const int wr  = w >> 1, wc = w & 1;
    const int lr  = l & 15, lg = l >> 4;

    const int blr = tid & 15;
    const int bng = tid >> 4;
    const int k0c = blr * 4;
    const int n0t = bng * 8;

    f32x4 acc[4][4];
#pragma unroll
    for (int i = 0; i < 4; ++i)
#pragma unroll
        for (int j = 0; j < 4; ++j) acc[i][j] = (f32x4){0.f, 0.f, 0.f, 0.f};

    for (int k0 = 0; k0 < K; k0 += 64) {
        uint4 av[4], bv[4];
#pragma unroll
        for (int i = 0; i < 4; ++i) {
            int c = tid + 256 * i;
            int m = c & 127, kc = c >> 7;
            av[i] = *(const uint4*)(A + (size_t)(m0 + m) * K + k0 + kc * 8);
        }
#pragma unroll
        for (int dk = 0; dk < 4; ++dk)
            bv[dk] = *(const uint4*)(X + (size_t)(k0 + k0c + dk) * N + n0 + n0t);

        __syncthreads();
#pragma unroll
        for (int i = 0; i < 4; ++i) {
            int c = tid + 256 * i;
            int m = c & 127, kc = c >> 7;
            *(uint4*)&As[m][kc * 8] = av[i];
        }
#pragma unroll
        for (int j = 0; j < 8; ++j) {
            ushort4 wv;
            wv.x = ((const ushort*)&bv[0])[j];
            wv.y = ((const ushort*)&bv[1])[j];
            wv.z = ((const ushort*)&bv[2])[j];
            wv.w = ((const ushort*)&bv[3])[j];
            *(ushort4*)&Bs[n0t + j][k0c] = wv;
        }
        __syncthreads();

#pragma unroll
        for (int ks = 0; ks < 2; ++ks) {
            short8 af[4], bf[4];
#pragma unroll
            for (int mf = 0; mf < 4; ++mf)
                af[mf] = *(const short8*)&As[wr * 64 + mf * 16 + lr][ks * 32 + lg * 8];
#pragma unroll
            for (int nf = 0; nf < 4; ++nf)
                bf[nf] = *(const short8*)&Bs[wc * 64 + nf * 16 + lr][ks * 32 + lg * 8];
#pragma unroll
            for (int mf = 0; mf < 4; ++mf)
#pragma unroll
                for (int nf = 0; nf < 4; ++nf)
                    acc[mf][nf] = __builtin_amdgcn_mfma_f32_16x16x32_bf16(
                        af[mf], bf[nf], acc[mf][nf], 0, 0, 0);
        }
    }

#pragma unroll
    for (int mf = 0; mf < 4; ++mf) {
#pragma unroll
        for (int r = 0; r < 4; ++r) {
            int m = m0 + wr * 64 + mf * 16 + lg * 4 + r;
            float bi = bias[m];
#pragma unroll
            for (int nf = 0; nf < 4; ++nf) {
                int n = n0 + wc * 64 + nf * 16 + lr;
                float v = acc[mf][nf][r] + bi;
                if (BF16OUT)
                    ((ushort*)Yg)[(size_t)b * M * N + (size_t)m * N + n] = f2bf(v);
                else
                    ((float*)Yg)[(size_t)b * M * N + (size_t)m * N + n] = v;
            }
        }
    }
}

// ---------------- fused dw5+gelu+dw3+gelu (LDS tiled, bf16 io) ----------------
__global__ __launch_bounds__(256) void k_dw_fused(
    const ushort* __restrict__ X, const float* __restrict__ W5,
    const float* __restrict__ B5, const float* __restrict__ W3,
    const float* __restrict__ B3, ushort* __restrict__ Y)
{
    const int b = blockIdx.z, ch = blockIdx.y;
    const int ty0 = (blockIdx.x >> 1) * 64, tx0 = (blockIdx.x & 1) * 64;
    __shared__ ushort in_s[70][72];
    __shared__ float  mid_s[66][68];
    const ushort* Xc = X + ((size_t)b * C6 + ch) * HW2;
    ushort* Yc = Y + ((size_t)b * C6 + ch) * HW2;
    const int tid = threadIdx.x;

    float w5[25], w3[9];
#pragma unroll
    for (int i = 0; i < 25; ++i) w5[i] = W5[ch * 25 + i];
#pragma unroll
    for (int i = 0; i < 9; ++i)  w3[i] = W3[ch * 9 + i];
    const float b5v = B5[ch], b3v = B3[ch];

    for (int e = tid; e < 70 * 72; e += 256) {
        int r = e / 72, c = e - r * 72;
        int gy = ty0 + r - 3, gx = tx0 + c - 3;
        ushort v = 0;
        if (c < 70 && (unsigned)gy < 128u && (unsigned)gx < 128u)
            v = Xc[gy * 128 + gx];
        in_s[r][c] = v;
    }
    __syncthreads();

    for (int g = tid; g < 66 * 17; g += 256) {
        int r = g / 17, cg = g - r * 17;
        int c = cg * 4;
        float xin[5][8];
#pragma unroll
        for (int dr = 0; dr < 5; ++dr) {
            ushort4 lo = *(const ushort4*)&in_s[r + dr][c];
            ushort4 hi = *(const ushort4*)&in_s[r + dr][c + 4];
            xin[dr][0] = bf2f(lo.x); xin[dr][1] = bf2f(lo.y);
            xin[dr][2] = bf2f(lo.z); xin[dr][3] = bf2f(lo.w);
            xin[dr][4] = bf2f(hi.x); xin[dr][5] = bf2f(hi.y);
            xin[dr][6] = bf2f(hi.z); xin[dr][7] = bf2f(hi.w);
        }
        int gy = ty0 + r - 1;
        float o[4];
#pragma unroll
        for (int j = 0; j < 4; ++j) {
            float acc = b5v;
#pragma unroll
            for (int dr = 0; dr < 5; ++dr)
#pragma unroll
                for (int dc = 0; dc < 5; ++dc)
                    acc += xin[dr][j + dc] * w5[dr * 5 + dc];
            int gx = tx0 + c + j - 1;
            bool ok = ((unsigned)gy < 128u) && ((unsigned)gx < 128u);
            o[j] = ok ? gelu(acc) : 0.f;
        }
        *(float4*)&mid_s[r][c] = make_float4(o[0], o[1], o[2], o[3]);
    }
    __syncthreads();

    for (int g = tid; g < 64 * 16; g += 256) {
        int r = g >> 4, c = (g & 15) * 4;
        float mv[3][8];
#pragma unroll
        for (int dr = 0; dr < 3; ++dr) {
            float4 a = *(const float4*)&mid_s[r + dr][c];
            float4 bq = *(const float4*)&mid_s[r + dr][c + 4];
            mv[dr][0] = a.x; mv[dr][1] = a.y; mv[dr][2] = a.z; mv[dr][3] = a.w;
            mv[dr][4] = bq.x; mv[dr][5] = bq.y; mv[dr][6] = bq.z; mv[dr][7] = bq.w;
        }
        ushort4 ov;
        float oo[4];
#pragma unroll
        for (int j = 0; j < 4; ++j) {
            float acc = b3v;
#pragma unroll
            for (int dr = 0; dr < 3; ++dr)
#pragma unroll
                for (int dc = 0; dc < 3; ++dc)
                    acc += mv[dr][j + dc] * w3[dr * 3 + dc];
            oo[j] = gelu(acc);
        }
        ov.x = f2bf(oo[0]); ov.y = f2bf(oo[1]); ov.z = f2bf(oo[2]); ov.w = f2bf(oo[3]);
        *(ushort4*)&Yc[(ty0 + r) * 128 + tx0 + c] = ov;
    }
}

// ---------------- IDWT (bf16 in/out) + global-mean partial sums ----------------
__global__ __launch_bounds__(256) void k_idwt(
    const ushort* __restrict__ S, const float* __restrict__ filt,
    ushort* __restrict__ Xw, float* __restrict__ sumbuf)
{
    const int b = blockIdx.z, c = blockIdx.y;
    const int tid = threadIdx.x;
    const int n = blockIdx.x * 256 + tid;
    const int h2 = n >> 7, w2 = n & 127;
    float f[16];
#pragma unroll
    for (int i = 0; i < 16; ++i) f[i] = filt[i];
    float sv[4];
#pragma unroll
    for (int k = 0; k < 4; ++k)
        sv[k] = bf2f(S[((size_t)b * C4 + k * CDIM + c) * HW2 + n]);
    ushort* xp = Xw + ((size_t)b * CDIM + c) * HW + (size_t)(2 * h2) * WDIM + 2 * w2;
    float local = 0.f;
#pragma unroll
    for (int p = 0; p < 2; ++p) {
        float v0 = sv[0] * f[0*4 + p*2 + 0] + sv[1] * f[1*4 + p*2 + 0]
                 + sv[2] * f[2*4 + p*2 + 0] + sv[3] * f[3*4 + p*2 + 0];
        float v1 = sv[0] * f[0*4 + p*2 + 1] + sv[1] * f[1*4 + p*2 + 1]
                 + sv[2] * f[2*4 + p*2 + 1] + sv[3] * f[3*4 + p*2 + 1];
        unsigned pk = (unsigned)f2bf(v0) | ((unsigned)f2bf(v1) << 16);
        *(unsigned*)&xp[p * WDIM] = pk;
        local += v0 + v1;
    }
    __shared__ float red[256];
    red[tid] = local;
    __syncthreads();
    for (int off = 128; off > 0; off >>= 1) {
        if (tid < off) red[tid] += red[tid + off];
        __syncthreads();
    }
    if (tid == 0) atomicAdd(&sumbuf[b * CDIM + c], red[0]);
}

// ---------------- SCA attention vector (tiny) ----------------
__global__ void k_att(const float* __restrict__ sumbuf, const float* __restrict__ Wsca,
                      const float* __restrict__ bsca, float* __restrict__ att)
{
    int t = threadIdx.x;
    int b = t >> 6, o = t & 63;
    float acc = bsca[o];
    const float s = 1.0f / (float)HW;
    for (int c = 0; c < 64; ++c)
        acc += Wsca[o * 64 + c] * (sumbuf[b * 64 + c] * s);
    att[t] = acc;
}

// ---------------- x*att -> pw3 -> y = x_in + x*beta (s_load weights, no LDS) ----------------
__global__ __launch_bounds__(256) void k_sca_pw3(
    const ushort* __restrict__ Xw, const float* __restrict__ Xin,
    const float* __restrict__ att, const float* __restrict__ W3,
    const float* __restrict__ b3, const float* __restrict__ beta,
    float* __restrict__ Yb)
{
    const int tid = threadIdx.x, b = blockIdx.z;
    const size_t n = (size_t)blockIdx.x * 256 + tid;
    const size_t base = (size_t)b * 64 * HW + n;
    const float* attb = att + b * 64;
    float v[64];
#pragma unroll
    for (int c = 0; c < 64; ++c)
        v[c] = bf2f(Xw[base + (size_t)c * HW]) * attb[c];
    for (int o = 0; o < 64; ++o) {
        const float* w = W3 + o * 64;
        float a0 = 0.f, a1 = 0.f, a2 = 0.f, a3 = 0.f;
#pragma unroll
        for (int c = 0; c < 64; c += 4) {
            a0 += w[c]   * v[c];   a1 += w[c+1] * v[c+1];
            a2 += w[c+2] * v[c+2]; a3 += w[c+3] * v[c+3];
        }
        Yb[base + (size_t)o * HW] = Xin[base + (size_t)o * HW]
                                  + (((a0 + a1) + (a2 + a3)) + b3[o]) * beta[o];
    }
}

// ---------------- fused LN2 -> pw4 -> SimpleGate -> pw5 -> out ----------------
// LN folded into pre-scaled weights: a_j = rs*(W4L_j·y - mu*Ma_j) + Ka_j
// pw5 applied as rank-1 updates so h never leaves registers.
__global__ __launch_bounds__(256) void k_tail2(
    const float* __restrict__ Yb, const float* __restrict__ W4L,
    const float* __restrict__ KaMa, const float* __restrict__ W5T,
    const float* __restrict__ b5, const float* __restrict__ gamma,
    float* __restrict__ Out)
{
    const int tid = threadIdx.x, b = blockIdx.z;
    const size_t n = (size_t)blockIdx.x * 256 + tid;
    const size_t base = (size_t)b * 64 * HW + n;
    float y[64];
    float s = 0.f, q = 0.f;
#pragma unroll
    for (int c = 0; c < 64; ++c) {
        float yv = Yb[base + (size_t)c * HW];
        y[c] = yv; s += yv; q += yv * yv;
    }
    const float mu = s * (1.0f / 64.0f);
    const float var = q * (1.0f / 64.0f) - mu * mu;
    const float rs = rsqrtf(fmaxf(var, 0.f) + 1e-6f);
    float acc[64];
#pragma unroll
    for (int o = 0; o < 64; ++o) acc[o] = b5[o];
    for (int j = 0; j < 64; ++j) {
        const float* wa = W4L + j * 64;
        const float* wg = W4L + (j + 64) * 64;
        float a0=0.f,a1=0.f,a2=0.f,a3=0.f,g0=0.f,g1=0.f,g2=0.f,g3=0.f;
#pragma unroll
        for (int c = 0; c < 64; c += 4) {
            a0 += wa[c]   * y[c];   a1 += wa[c+1] * y[c+1];
            a2 += wa[c+2] * y[c+2]; a3 += wa[c+3] * y[c+3];
            g0 += wg[c]   * y[c];   g1 += wg[c+1] * y[c+1];
            g2 += wg[c+2] * y[c+2]; g3 += wg[c+3] * y[c+3];
        }
        float aj = rs * (((a0 + a1) + (a2 + a3)) - mu * KaMa[128 + j]) + KaMa[j];
        float gj = rs * (((g0 + g1) + (g2 + g3)) - mu * KaMa[192 + j]) + KaMa[64 + j];
        float hj = aj * gj;
        const float* w5r = W5T + j * 64;
#pragma unroll
        for (int o = 0; o < 64; ++o) acc[o] += w5r[o] * hj;
    }
#pragma unroll
    for (int o = 0; o < 64; ++o)
        Out[base + (size_t)o * HW] = y[o] + acc[o] * gamma[o];
}

extern "C" void kernel_launch(void* const* d_in, const int* in_sizes, int n_in,
                              void* d_out, int out_size, void* d_ws, size_t ws_size,
                              hipStream_t stream) {
    const float* x_in  = (const float*)d_in[0];
    const float* filt  = (const float*)d_in[1];
    const float* ln1_w = (const float*)d_in[2];
    const float* ln1_b = (const float*)d_in[3];
    const float* w1    = (const float*)d_in[4];
    const float* b1    = (const float*)d_in[5];
    const float* dw5   = (const float*)d_in[6];
    const float* bdw5  = (const float*)d_in[7];
    const float* dw3   = (const float*)d_in[8];
    const float* bdw3  = (const float*)d_in[9];
    const float* w2    = (const float*)d_in[10];
    const float* b2    = (const float*)d_in[11];
    const float* w_sca = (const float*)d_in[12];
    const float* b_sca = (const float*)d_in[13];
    const float* w3    = (const float*)d_in[14];
    const float* b3    = (const float*)d_in[15];
    const float* beta  = (const float*)d_in[16];
    const float* ln2_w = (const float*)d_in[17];
    const float* ln2_b = (const float*)d_in[18];
    const float* w4    = (const float*)d_in[19];
    const float* b4    = (const float*)d_in[20];
    const float* w5    = (const float*)d_in[21];
    const float* b5    = (const float*)d_in[22];
    const float* gamma = (const float*)d_in[23];
    float* out = (float*)d_out;

    const size_t PB = (size_t)CDIM * HW * 4;   // 16 MiB per-batch region
    int bc = 8;
    while (bc > 1 && 3 * PB * (size_t)bc + 512 * 1024 > ws_size) bc >>= 1;
    const int nchunk = BDIM / bc;

    char* base = (char*)d_ws;
    char* R1 = base;
    char* R2 = base + PB * bc;
    char* R3 = base + 2 * PB * bc;
    ushort* w1b  = (ushort*)(base + 3 * PB * bc);
    ushort* w2b  = w1b + C6 * C4;
    float*  w4l  = (float*)(w2b + C6 * C4);    // [128*64]
    float*  kama = w4l + 128 * 64;             // [256] : Ka(0..127), Ma(128..255)
    float*  w5t  = kama + 256;                 // [64*64]
    float*  stats = w5t + 64 * 64;             // [bc*64]
    float*  attv  = stats + (size_t)bc * 64;   // [bc*64]

    // per-call weight prep (ws is re-poisoned every timed call)
    k_cvt_bf16<<<(C6 * C4 + 255) / 256, 256, 0, stream>>>(w1, w1b, C6 * C4);
    k_cvt_bf16<<<(C6 * C4 + 255) / 256, 256, 0, stream>>>(w2, w2b, C6 * C4);
    k_prep<<<1, 256, 0, stream>>>(w4, b4, ln2_w, ln2_b, w5, w4l, kama, w5t);

    // packed views (lifetimes verified):
    ushort* S   = (ushort*)R1;  // ln_dwt -> pw1
    ushort* p1  = (ushort*)R2;  // pw1 -> dw
    ushort* d3  = (ushort*)R1;  // dw -> pw2      (S dead)
    ushort* p2  = (ushort*)R2;  // pw2 -> idwt    (p1 dead)
    ushort* xw  = (ushort*)R3;  // idwt -> sca_pw3
    float*  yb  = (float*)R1;   // sca_pw3 -> tail2  (d3 dead)

    for (int ck = 0; ck < nchunk; ++ck) {
        const float* xin_c = x_in + (size_t)ck * bc * CDIM * HW;
        float* out_c = out + (size_t)ck * bc * CDIM * HW;

        hipMemsetAsync(stats, 0, (size_t)bc * 64 * sizeof(float), stream);

        k_ln_dwt<<<dim3(128, 1, bc), 256, 0, stream>>>(xin_c, filt, ln1_w, ln1_b, S);
        k_pw_mfma<true><<<dim3(128, 3, bc), 256, 0, stream>>>(w1b, b1, S,  (void*)p1, C6, C4, HW2);
        k_dw_fused<<<dim3(4, C6, bc), 256, 0, stream>>>(p1, dw5, bdw5, dw3, bdw3, d3);
        k_pw_mfma<true><<<dim3(128, 2, bc), 256, 0, stream>>>(w2b, b2, d3, (void*)p2, C4, C6, HW2);
        k_idwt<<<dim3(64, CDIM, bc), 256, 0, stream>>>(p2, filt, xw, stats);
        k_att<<<1, bc * 64, 0, stream>>>(stats, w_sca, b_sca, attv);
        k_sca_pw3<<<dim3(256, 1, bc), 256, 0, stream>>>(xw, xin_c, attv, w3, b3, beta, yb);
        k_tail2<<<dim3(256, 1, bc), 256, 0, stream>>>(yb, w4l, kama, w5t, b5, gamma, out_c);
    }
}